// Round 1
// baseline (563.593 us; speedup 1.0000x reference)
//
#include <hip/hip_runtime.h>
#include <hip/hip_bf16.h>

#define N_NODES 50000
#define N_EDGES 600000
#define N_GRAPHS 256
#define D 128

// ---------------- CSR build ----------------

__global__ void zero_int_kernel(int* __restrict__ p, int n) {
    int i = blockIdx.x * 256 + threadIdx.x;
    if (i < n) p[i] = 0;
}

__global__ void deg_kernel(const int* __restrict__ dst, int* __restrict__ deg) {
    int e = blockIdx.x * 256 + threadIdx.x;
    if (e < N_EDGES) atomicAdd(&deg[dst[e]], 1);
}

// single-block exclusive scan over deg -> row_start, cursor, deg_inv
__global__ __launch_bounds__(1024) void scan_kernel(const int* __restrict__ deg,
                                                    int* __restrict__ row_start,
                                                    int* __restrict__ cursor,
                                                    float* __restrict__ deg_inv) {
    __shared__ int tmp[1024];
    __shared__ int carry_s;
    int tid = threadIdx.x;
    if (tid == 0) carry_s = 0;
    __syncthreads();
    for (int base = 0; base < N_NODES; base += 1024) {
        int i = base + tid;
        int v = (i < N_NODES) ? deg[i] : 0;
        tmp[tid] = v;
        __syncthreads();
        for (int off = 1; off < 1024; off <<= 1) {
            int add = (tid >= off) ? tmp[tid - off] : 0;
            __syncthreads();
            tmp[tid] += add;
            __syncthreads();
        }
        int incl = tmp[tid];
        int carry = carry_s;
        if (i < N_NODES) {
            int rs = carry + incl - v;  // exclusive
            row_start[i] = rs;
            cursor[i] = rs;
            deg_inv[i] = 1.0f / fmaxf((float)v, 1.0f);
        }
        __syncthreads();
        if (tid == 1023) carry_s = carry + incl;
        __syncthreads();
    }
    if (tid == 0) row_start[N_NODES] = carry_s;
}

__global__ void fill_kernel(const int* __restrict__ src, const int* __restrict__ dst,
                            int* __restrict__ cursor, int* __restrict__ csr_src) {
    int e = blockIdx.x * 256 + threadIdx.x;
    if (e < N_EDGES) {
        int slot = atomicAdd(&cursor[dst[e]], 1);
        csr_src[slot] = src[e];
    }
}

// ---------------- pre layer: h0 = relu(x @ W_pre + b_pre) ----------------

__global__ void pre_kernel(const float* __restrict__ x, const float* __restrict__ Wp,
                           const float* __restrict__ bp, float* __restrict__ h0) {
    int idx = blockIdx.x * 256 + threadIdx.x;  // node*128 + j
    if (idx >= N_NODES * D) return;
    int node = idx >> 7, j = idx & 127;
    const float* xr = x + node * 5;
    float acc = bp[j];
#pragma unroll
    for (int k = 0; k < 5; ++k) acc += xr[k] * Wp[k * D + j];
    h0[idx] = fmaxf(acc, 0.0f);
}

// ---------------- mean aggregate: agg[n] = deg_inv[n] * sum_{src in N(n)} h[src] ----------------

__global__ __launch_bounds__(256) void agg_kernel(const float* __restrict__ h,
                                                  const int* __restrict__ row_start,
                                                  const int* __restrict__ csr_src,
                                                  const float* __restrict__ deg_inv,
                                                  float* __restrict__ agg) {
    int node = blockIdx.x * 4 + (threadIdx.x >> 6);
    int lane = threadIdx.x & 63;
    if (node >= N_NODES) return;
    int s = row_start[node], e = row_start[node + 1];
    float a0 = 0.f, a1 = 0.f;
    for (int i = s; i < e; ++i) {
        const float* hp = h + (size_t)csr_src[i] * D;
        a0 += hp[lane];
        a1 += hp[lane + 64];
    }
    float di = deg_inv[node];
    size_t o = (size_t)node * D;
    agg[o + lane] = a0 * di;
    agg[o + lane + 64] = a1 * di;
}

// ---------------- fused SAGE linear: hout = relu(l2norm(agg@Wl + b + hin@Wr)) ----------------

#define TM 32     // rows per block
#define SLAB 16   // K rows of W staged per iteration

__global__ __launch_bounds__(256) void lin_kernel(const float* __restrict__ hin,
                                                  const float* __restrict__ agg,
                                                  const float* __restrict__ Wl,
                                                  const float* __restrict__ b,
                                                  const float* __restrict__ Wr,
                                                  float* __restrict__ hout) {
    __shared__ __align__(16) float Aa[D][TM + 4];   // agg^T, pad 36 (16B-aligned rows)
    __shared__ __align__(16) float Ah[D][TM + 4];   // hin^T
    __shared__ __align__(16) float Wls[SLAB][D];
    __shared__ __align__(16) float Wrs[SLAB][D];

    int t = threadIdx.x;
    int row0 = blockIdx.x * TM;

    // load A tiles transposed: Aa[k][r] = agg[row0+r][k]
    for (int i = t; i < TM * D; i += 256) {
        int r = i >> 7, k = i & 127;
        int row = row0 + r;
        float va = 0.f, vh = 0.f;
        if (row < N_NODES) {
            va = agg[(size_t)row * D + k];
            vh = hin[(size_t)row * D + k];
        }
        Aa[k][r] = va;
        Ah[k][r] = vh;
    }

    int tx = t & 31, ty = t >> 5;
    int tx4 = tx * 4, ty4 = ty * 4;

    float acc[4][4];
#pragma unroll
    for (int r = 0; r < 4; ++r)
#pragma unroll
        for (int c = 0; c < 4; ++c) acc[r][c] = 0.f;

    for (int s = 0; s < D / SLAB; ++s) {
        __syncthreads();
        // stage W slab
        for (int i = t; i < SLAB * D / 4; i += 256) {
            int k = i >> 5, j4 = (i & 31) * 4;
            float4 wl = *(const float4*)&Wl[(s * SLAB + k) * D + j4];
            float4 wr = *(const float4*)&Wr[(s * SLAB + k) * D + j4];
            *(float4*)&Wls[k][j4] = wl;
            *(float4*)&Wrs[k][j4] = wr;
        }
        __syncthreads();
#pragma unroll
        for (int k = 0; k < SLAB; ++k) {
            int kk = s * SLAB + k;
            float4 aa = *(const float4*)&Aa[kk][ty4];
            float4 ah = *(const float4*)&Ah[kk][ty4];
            float4 wl = *(const float4*)&Wls[k][tx4];
            float4 wr = *(const float4*)&Wrs[k][tx4];
            float ar[4] = {aa.x, aa.y, aa.z, aa.w};
            float hr[4] = {ah.x, ah.y, ah.z, ah.w};
            float wlc[4] = {wl.x, wl.y, wl.z, wl.w};
            float wrc[4] = {wr.x, wr.y, wr.z, wr.w};
#pragma unroll
            for (int r = 0; r < 4; ++r)
#pragma unroll
                for (int c = 0; c < 4; ++c)
                    acc[r][c] += ar[r] * wlc[c] + hr[r] * wrc[c];
        }
    }

    // epilogue: + bias, per-row L2 normalize (over 32 lanes * 4 cols), relu, store
    float4 b4 = *(const float4*)&b[tx4];
    float bb[4] = {b4.x, b4.y, b4.z, b4.w};
#pragma unroll
    for (int r = 0; r < 4; ++r) {
        float v[4];
        float ss = 0.f;
#pragma unroll
        for (int c = 0; c < 4; ++c) {
            v[c] = acc[r][c] + bb[c];
            ss += v[c] * v[c];
        }
#pragma unroll
        for (int m = 16; m >= 1; m >>= 1) ss += __shfl_xor(ss, m);
        float inv = 1.0f / fmaxf(sqrtf(ss), 1e-12f);
        int row = row0 + ty4 + r;
        if (row < N_NODES) {
            float4 o;
            o.x = fmaxf(v[0] * inv, 0.f);
            o.y = fmaxf(v[1] * inv, 0.f);
            o.z = fmaxf(v[2] * inv, 0.f);
            o.w = fmaxf(v[3] * inv, 0.f);
            *(float4*)&hout[(size_t)row * D + tx4] = o;
        }
    }
}

// ---------------- global mean pool (batch is sorted -> binary search ranges) ----------------

__global__ __launch_bounds__(128) void pool_kernel(const float* __restrict__ h,
                                                   const int* __restrict__ batch,
                                                   float* __restrict__ g) {
    int gid = blockIdx.x;  // graph id
    int j = threadIdx.x;   // feature
    int lo = 0, hi = N_NODES;
    while (lo < hi) { int m = (lo + hi) >> 1; if (batch[m] < gid) lo = m + 1; else hi = m; }
    int start = lo;
    lo = start; hi = N_NODES;
    while (lo < hi) { int m = (lo + hi) >> 1; if (batch[m] < gid + 1) lo = m + 1; else hi = m; }
    int end = lo;
    float s = 0.f;
    for (int i = start; i < end; ++i) s += h[(size_t)i * D + j];
    float cnt = (float)(end - start);
    g[gid * D + j] = s / fmaxf(cnt, 1.0f);
}

// ---------------- head MLP ----------------

__global__ __launch_bounds__(128) void mlp_kernel(const float* __restrict__ g,
                                                  const float* __restrict__ Wp1,
                                                  const float* __restrict__ bp1,
                                                  const float* __restrict__ Wp2,
                                                  const float* __restrict__ bp2,
                                                  const float* __restrict__ Wout,
                                                  const float* __restrict__ bout,
                                                  float* __restrict__ out) {
    __shared__ float gin[128], y1[128], y2[64];
    int gid = blockIdx.x, j = threadIdx.x;
    gin[j] = g[gid * 128 + j];
    __syncthreads();
    float a = bp1[j];
    for (int k = 0; k < 128; ++k) a += gin[k] * Wp1[k * 128 + j];
    y1[j] = fmaxf(a, 0.f);
    __syncthreads();
    if (j < 64) {
        float a2 = bp2[j];
        for (int k = 0; k < 128; ++k) a2 += y1[k] * Wp2[k * 64 + j];
        y2[j] = fmaxf(a2, 0.f);
    }
    __syncthreads();
    if (j < 64) {
        float v = y2[j] * Wout[j];
#pragma unroll
        for (int m = 32; m >= 1; m >>= 1) v += __shfl_xor(v, m);
        if (j == 0) out[gid] = v + bout[0];
    }
}

// ---------------- launch ----------------

extern "C" void kernel_launch(void* const* d_in, const int* in_sizes, int n_in,
                              void* d_out, int out_size, void* d_ws, size_t ws_size,
                              hipStream_t stream) {
    const float* x     = (const float*)d_in[0];
    const int*   ei    = (const int*)d_in[1];
    const int*   batch = (const int*)d_in[2];
    const float* W_pre = (const float*)d_in[3];
    const float* b_pre = (const float*)d_in[4];
    const float* W1_l  = (const float*)d_in[5];
    const float* b1    = (const float*)d_in[6];
    const float* W1_r  = (const float*)d_in[7];
    const float* W2_l  = (const float*)d_in[8];
    const float* b2    = (const float*)d_in[9];
    const float* W2_r  = (const float*)d_in[10];
    const float* W_p1  = (const float*)d_in[11];
    const float* b_p1  = (const float*)d_in[12];
    const float* W_p2  = (const float*)d_in[13];
    const float* b_p2  = (const float*)d_in[14];
    const float* W_out = (const float*)d_in[15];
    const float* b_out = (const float*)d_in[16];

    const int* src = ei;
    const int* dst = ei + N_EDGES;

    // workspace carve-out (256B aligned)
    size_t off = 0;
    auto carve = [&](size_t bytes) {
        void* p = (char*)d_ws + off;
        off += (bytes + 255) & ~(size_t)255;
        return p;
    };
    int*   deg       = (int*)carve(N_NODES * 4);
    int*   row_start = (int*)carve((N_NODES + 1) * 4);
    int*   cursor    = (int*)carve(N_NODES * 4);
    int*   csr_src   = (int*)carve(N_EDGES * 4);
    float* deg_inv   = (float*)carve(N_NODES * 4);
    float* h0        = (float*)carve((size_t)N_NODES * D * 4);
    float* agg       = (float*)carve((size_t)N_NODES * D * 4);
    float* h1        = (float*)carve((size_t)N_NODES * D * 4);
    float* g         = (float*)carve(N_GRAPHS * D * 4);
    float* h2        = h0;  // reuse: h0 dead after conv1's lin
    float* out       = (float*)d_out;

    // CSR build
    zero_int_kernel<<<(N_NODES + 255) / 256, 256, 0, stream>>>(deg, N_NODES);
    deg_kernel<<<(N_EDGES + 255) / 256, 256, 0, stream>>>(dst, deg);
    scan_kernel<<<1, 1024, 0, stream>>>(deg, row_start, cursor, deg_inv);
    fill_kernel<<<(N_EDGES + 255) / 256, 256, 0, stream>>>(src, dst, cursor, csr_src);

    // pre layer
    pre_kernel<<<(N_NODES * D + 255) / 256, 256, 0, stream>>>(x, W_pre, b_pre, h0);

    // conv1
    agg_kernel<<<(N_NODES + 3) / 4, 256, 0, stream>>>(h0, row_start, csr_src, deg_inv, agg);
    lin_kernel<<<(N_NODES + TM - 1) / TM, 256, 0, stream>>>(h0, agg, W1_l, b1, W1_r, h1);

    // conv2
    agg_kernel<<<(N_NODES + 3) / 4, 256, 0, stream>>>(h1, row_start, csr_src, deg_inv, agg);
    lin_kernel<<<(N_NODES + TM - 1) / TM, 256, 0, stream>>>(h1, agg, W2_l, b2, W2_r, h2);

    // pool + head
    pool_kernel<<<N_GRAPHS, 128, 0, stream>>>(h2, batch, g);
    mlp_kernel<<<N_GRAPHS, 128, 0, stream>>>(g, W_p1, b_p1, W_p2, b_p2, W_out, b_out, out);
}

// Round 2
// 315.903 us; speedup vs baseline: 1.7841x; 1.7841x over previous
//
#include <hip/hip_runtime.h>
#include <hip/hip_bf16.h>

#define N_NODES 50000
#define N_EDGES 600000
#define N_GRAPHS 256
#define D 128
#define NTILES 1563  // ceil(50000/32)

typedef __bf16 bf16x8 __attribute__((ext_vector_type(8)));
typedef float f32x16 __attribute__((ext_vector_type(16)));

__device__ __forceinline__ float bf2f(unsigned short u) {
    unsigned v = ((unsigned)u) << 16;
    return __builtin_bit_cast(float, v);
}
__device__ __forceinline__ unsigned short f2bf(float f) {
    unsigned x = __builtin_bit_cast(unsigned, f);
    unsigned r = (x + 0x7fffu + ((x >> 16) & 1u)) >> 16;  // RTN-even
    return (unsigned short)r;
}

// ---------------- CSR build ----------------

__global__ void zero_int_kernel(int* __restrict__ p, int n) {
    int i = blockIdx.x * 256 + threadIdx.x;
    if (i < n) p[i] = 0;
}

__global__ void deg_kernel(const int* __restrict__ dst, int* __restrict__ deg) {
    int e = blockIdx.x * 256 + threadIdx.x;
    if (e < N_EDGES) atomicAdd(&deg[dst[e]], 1);
}

// hierarchical scan: per-block exclusive partials + block sums
__global__ __launch_bounds__(1024) void scan_blk_kernel(const int* __restrict__ deg,
                                                        int* __restrict__ partial,
                                                        int* __restrict__ bsum) {
    __shared__ int tmp[1024];
    int tid = threadIdx.x;
    int i = blockIdx.x * 1024 + tid;
    int v = (i < N_NODES) ? deg[i] : 0;
    tmp[tid] = v;
    __syncthreads();
    for (int off = 1; off < 1024; off <<= 1) {
        int add = (tid >= off) ? tmp[tid - off] : 0;
        __syncthreads();
        tmp[tid] += add;
        __syncthreads();
    }
    if (i < N_NODES) partial[i] = tmp[tid] - v;  // exclusive within block
    if (tid == 1023) bsum[blockIdx.x] = tmp[tid];
}

__global__ void scan_top_kernel(const int* __restrict__ bsum, int* __restrict__ boff,
                                int* __restrict__ row_start, int nblk) {
    int l = threadIdx.x;  // 64 threads, one wave
    int v = (l < nblk) ? bsum[l] : 0;
    int incl = v;
#pragma unroll
    for (int m = 1; m < 64; m <<= 1) {
        int t = __shfl_up(incl, m);
        if (l >= m) incl += t;
    }
    if (l < nblk) boff[l] = incl - v;
    if (l == 63) row_start[N_NODES] = incl;  // grand total
}

__global__ void scan_fix_kernel(const int* __restrict__ partial, const int* __restrict__ boff,
                                const int* __restrict__ deg, int* __restrict__ row_start,
                                int* __restrict__ cursor, float* __restrict__ deg_inv) {
    int i = blockIdx.x * 256 + threadIdx.x;
    if (i >= N_NODES) return;
    int rs = partial[i] + boff[i >> 10];
    row_start[i] = rs;
    cursor[i] = rs;
    deg_inv[i] = 1.0f / fmaxf((float)deg[i], 1.0f);
}

__global__ void fill_kernel(const int* __restrict__ src, const int* __restrict__ dst,
                            int* __restrict__ cursor, int* __restrict__ csr_src) {
    int e = blockIdx.x * 256 + threadIdx.x;
    if (e < N_EDGES) {
        int slot = atomicAdd(&cursor[dst[e]], 1);
        csr_src[slot] = src[e];
    }
}

// ---------------- weight pack: fragment-major bf16 [conv][kt][ct][lane][8] ----------------
// B-frag layout for mfma_f32_32x32x16_bf16: lane l holds B[k0+(l>>5)*8+j][ct*32+(l&31)]

__global__ void pack_w_kernel(const float* __restrict__ Wl1, const float* __restrict__ Wr1,
                              const float* __restrict__ Wl2, const float* __restrict__ Wr2,
                              unsigned short* __restrict__ Wp) {
    int tid = blockIdx.x * 256 + threadIdx.x;  // < 65536
    int conv = tid >> 15;
    int e = tid & 32767;
    int j = e & 7, lane = (e >> 3) & 63, ct = (e >> 9) & 3, kt = e >> 11;
    int k = kt * 16 + (lane >> 5) * 8 + j;
    int col = ct * 32 + (lane & 31);
    const float* Wl = conv ? Wl2 : Wl1;
    const float* Wr = conv ? Wr2 : Wr1;
    float v = (k < 128) ? Wl[k * 128 + col] : Wr[(k - 128) * 128 + col];
    Wp[tid] = f2bf(v);
}

// ---------------- pre layer: h0 = relu(x @ W_pre + b_pre) -> bf16 ----------------

__global__ void pre_kernel(const float* __restrict__ x, const float* __restrict__ Wp,
                           const float* __restrict__ bp, unsigned short* __restrict__ h0) {
    int idx = blockIdx.x * 256 + threadIdx.x;
    if (idx >= N_NODES * D) return;
    int node = idx >> 7, j = idx & 127;
    const float* xr = x + node * 5;
    float acc = bp[j];
#pragma unroll
    for (int k = 0; k < 5; ++k) acc += xr[k] * Wp[k * D + j];
    h0[idx] = f2bf(fmaxf(acc, 0.0f));
}

// ---------------- mean aggregate (bf16 in, f32 accum, bf16 out) ----------------

__global__ __launch_bounds__(256) void agg_kernel(const unsigned short* __restrict__ h,
                                                  const int* __restrict__ row_start,
                                                  const int* __restrict__ csr_src,
                                                  const float* __restrict__ deg_inv,
                                                  unsigned short* __restrict__ aggb) {
    int node = blockIdx.x * 4 + (threadIdx.x >> 6);
    int lane = threadIdx.x & 63;
    if (node >= N_NODES) return;
    int s = row_start[node], e = row_start[node + 1];
    float a0 = 0.f, a1 = 0.f;
    for (int i = s; i < e; ++i) {
        ushort2 u = *(const ushort2*)(h + (size_t)csr_src[i] * D + lane * 2);
        a0 += bf2f(u.x);
        a1 += bf2f(u.y);
    }
    float di = deg_inv[node];
    ushort2 o;
    o.x = f2bf(a0 * di);
    o.y = f2bf(a1 * di);
    *(ushort2*)(aggb + (size_t)node * D + lane * 2) = o;
}

// ---------------- fused SAGE linear via MFMA (no LDS, no barriers) ----------------
// out[row][col] = relu(l2norm_row( [agg|hin] @ Wp + b )), K=256, per wave 32 rows x 128 cols

__global__ __launch_bounds__(256) void lin_mfma_kernel(const unsigned short* __restrict__ hin,
                                                       const unsigned short* __restrict__ aggb,
                                                       const unsigned short* __restrict__ Wp,
                                                       const float* __restrict__ b,
                                                       unsigned short* __restrict__ hout) {
    int wg = blockIdx.x * 4 + (threadIdx.x >> 6);
    if (wg >= NTILES) return;
    int lane = threadIdx.x & 63;
    int l31 = lane & 31, hi = lane >> 5;
    int row0 = wg * 32;
    int rowg = row0 + l31;
    if (rowg > N_NODES - 1) rowg = N_NODES - 1;  // clamp loads; stores guarded

    const unsigned short* arow = aggb + (size_t)rowg * D + hi * 8;
    const unsigned short* hrow = hin + (size_t)rowg * D + hi * 8;
    const unsigned short* wbase = Wp + lane * 8;

    f32x16 acc[4];
#pragma unroll
    for (int ct = 0; ct < 4; ++ct) acc[ct] = (f32x16)(0.0f);

#pragma unroll
    for (int kt = 0; kt < 16; ++kt) {
        const unsigned short* asrc = (kt < 8) ? (arow + kt * 16) : (hrow + (kt - 8) * 16);
        bf16x8 af = *(const bf16x8*)asrc;
#pragma unroll
        for (int ct = 0; ct < 4; ++ct) {
            bf16x8 bfrag = *(const bf16x8*)(wbase + (kt * 4 + ct) * 512);
            acc[ct] = __builtin_amdgcn_mfma_f32_32x32x16_bf16(af, bfrag, acc[ct], 0, 0, 0);
        }
    }

    // epilogue: +bias, per-row L2 norm, relu, bf16 store
    float bb[4];
#pragma unroll
    for (int ct = 0; ct < 4; ++ct) bb[ct] = b[ct * 32 + l31];

#pragma unroll
    for (int r = 0; r < 16; ++r) {
        float v0 = acc[0][r] + bb[0];
        float v1 = acc[1][r] + bb[1];
        float v2 = acc[2][r] + bb[2];
        float v3 = acc[3][r] + bb[3];
        float ss = v0 * v0 + v1 * v1 + v2 * v2 + v3 * v3;
        ss += __shfl_xor(ss, 1);
        ss += __shfl_xor(ss, 2);
        ss += __shfl_xor(ss, 4);
        ss += __shfl_xor(ss, 8);
        ss += __shfl_xor(ss, 16);
        float sc = 1.0f / fmaxf(sqrtf(ss), 1e-12f);
        int row = row0 + (r & 3) + 8 * (r >> 2) + 4 * hi;
        if (row < N_NODES) {
            size_t o = (size_t)row * D + l31;
            hout[o] = f2bf(fmaxf(v0 * sc, 0.f));
            hout[o + 32] = f2bf(fmaxf(v1 * sc, 0.f));
            hout[o + 64] = f2bf(fmaxf(v2 * sc, 0.f));
            hout[o + 96] = f2bf(fmaxf(v3 * sc, 0.f));
        }
    }
}

// ---------------- global mean pool (bf16 in, f32 out) ----------------

__global__ __launch_bounds__(128) void pool_kernel(const unsigned short* __restrict__ h,
                                                   const int* __restrict__ batch,
                                                   float* __restrict__ g) {
    int gid = blockIdx.x;
    int j = threadIdx.x;
    int lo = 0, hi = N_NODES;
    while (lo < hi) { int m = (lo + hi) >> 1; if (batch[m] < gid) lo = m + 1; else hi = m; }
    int start = lo;
    lo = start; hi = N_NODES;
    while (lo < hi) { int m = (lo + hi) >> 1; if (batch[m] < gid + 1) lo = m + 1; else hi = m; }
    int end = lo;
    float s = 0.f;
    for (int i = start; i < end; ++i) s += bf2f(h[(size_t)i * D + j]);
    float cnt = (float)(end - start);
    g[gid * D + j] = s / fmaxf(cnt, 1.0f);
}

// ---------------- head MLP (f32) ----------------

__global__ __launch_bounds__(128) void mlp_kernel(const float* __restrict__ g,
                                                  const float* __restrict__ Wp1,
                                                  const float* __restrict__ bp1,
                                                  const float* __restrict__ Wp2,
                                                  const float* __restrict__ bp2,
                                                  const float* __restrict__ Wout,
                                                  const float* __restrict__ bout,
                                                  float* __restrict__ out) {
    __shared__ float gin[128], y1[128], y2[64];
    int gid = blockIdx.x, j = threadIdx.x;
    gin[j] = g[gid * 128 + j];
    __syncthreads();
    float a = bp1[j];
    for (int k = 0; k < 128; ++k) a += gin[k] * Wp1[k * 128 + j];
    y1[j] = fmaxf(a, 0.f);
    __syncthreads();
    if (j < 64) {
        float a2 = bp2[j];
        for (int k = 0; k < 128; ++k) a2 += y1[k] * Wp2[k * 64 + j];
        y2[j] = fmaxf(a2, 0.f);
    }
    __syncthreads();
    if (j < 64) {
        float v = y2[j] * Wout[j];
#pragma unroll
        for (int m = 32; m >= 1; m >>= 1) v += __shfl_xor(v, m);
        if (j == 0) out[gid] = v + bout[0];
    }
}

// ---------------- launch ----------------

extern "C" void kernel_launch(void* const* d_in, const int* in_sizes, int n_in,
                              void* d_out, int out_size, void* d_ws, size_t ws_size,
                              hipStream_t stream) {
    const float* x     = (const float*)d_in[0];
    const int*   ei    = (const int*)d_in[1];
    const int*   batch = (const int*)d_in[2];
    const float* W_pre = (const float*)d_in[3];
    const float* b_pre = (const float*)d_in[4];
    const float* W1_l  = (const float*)d_in[5];
    const float* b1    = (const float*)d_in[6];
    const float* W1_r  = (const float*)d_in[7];
    const float* W2_l  = (const float*)d_in[8];
    const float* b2    = (const float*)d_in[9];
    const float* W2_r  = (const float*)d_in[10];
    const float* W_p1  = (const float*)d_in[11];
    const float* b_p1  = (const float*)d_in[12];
    const float* W_p2  = (const float*)d_in[13];
    const float* b_p2  = (const float*)d_in[14];
    const float* W_out = (const float*)d_in[15];
    const float* b_out = (const float*)d_in[16];

    const int* src = ei;
    const int* dst = ei + N_EDGES;

    size_t off = 0;
    auto carve = [&](size_t bytes) {
        void* p = (char*)d_ws + off;
        off += (bytes + 255) & ~(size_t)255;
        return p;
    };
    int* deg       = (int*)carve(N_NODES * 4);
    int* row_start = (int*)carve((N_NODES + 1) * 4);
    int* cursor    = (int*)carve(N_NODES * 4);
    int* csr_src   = (int*)carve(N_EDGES * 4);
    float* deg_inv = (float*)carve(N_NODES * 4);
    int* partial   = (int*)carve(N_NODES * 4);
    int* bsum      = (int*)carve(64 * 4);
    int* boff      = (int*)carve(64 * 4);
    unsigned short* h0   = (unsigned short*)carve((size_t)N_NODES * D * 2);
    unsigned short* h1   = (unsigned short*)carve((size_t)N_NODES * D * 2);
    unsigned short* aggb = (unsigned short*)carve((size_t)N_NODES * D * 2);
    unsigned short* Wp   = (unsigned short*)carve(65536 * 2);
    float* g = (float*)carve(N_GRAPHS * D * 4);
    unsigned short* h2 = h0;  // reuse: h0 dead after lin1
    float* out = (float*)d_out;

    const int nblk_scan = (N_NODES + 1023) / 1024;  // 49

    pack_w_kernel<<<256, 256, 0, stream>>>(W1_l, W1_r, W2_l, W2_r, Wp);

    zero_int_kernel<<<(N_NODES + 255) / 256, 256, 0, stream>>>(deg, N_NODES);
    deg_kernel<<<(N_EDGES + 255) / 256, 256, 0, stream>>>(dst, deg);
    scan_blk_kernel<<<nblk_scan, 1024, 0, stream>>>(deg, partial, bsum);
    scan_top_kernel<<<1, 64, 0, stream>>>(bsum, boff, row_start, nblk_scan);
    scan_fix_kernel<<<(N_NODES + 255) / 256, 256, 0, stream>>>(partial, boff, deg,
                                                               row_start, cursor, deg_inv);
    fill_kernel<<<(N_EDGES + 255) / 256, 256, 0, stream>>>(src, dst, cursor, csr_src);

    pre_kernel<<<(N_NODES * D + 255) / 256, 256, 0, stream>>>(x, W_pre, b_pre, h0);

    // conv1
    agg_kernel<<<(N_NODES + 3) / 4, 256, 0, stream>>>(h0, row_start, csr_src, deg_inv, aggb);
    lin_mfma_kernel<<<(NTILES + 3) / 4, 256, 0, stream>>>(h0, aggb, Wp, b1, h1);

    // conv2
    agg_kernel<<<(N_NODES + 3) / 4, 256, 0, stream>>>(h1, row_start, csr_src, deg_inv, aggb);
    lin_mfma_kernel<<<(NTILES + 3) / 4, 256, 0, stream>>>(h1, aggb, Wp + 32768, b2, h2);

    pool_kernel<<<N_GRAPHS, 128, 0, stream>>>(h2, batch, g);
    mlp_kernel<<<N_GRAPHS, 128, 0, stream>>>(g, W_p1, b_p1, W_p2, b_p2, W_out, b_out, out);
}

// Round 3
// 225.479 us; speedup vs baseline: 2.4995x; 1.4010x over previous
//
#include <hip/hip_runtime.h>
#include <hip/hip_bf16.h>

#define N_NODES 50000
#define N_EDGES 600000
#define N_GRAPHS 256
#define D 128
#define NTILES 1563  // ceil(50000/32)

typedef __bf16 bf16x8 __attribute__((ext_vector_type(8)));
typedef float f32x16 __attribute__((ext_vector_type(16)));
typedef unsigned short u16x8 __attribute__((ext_vector_type(8)));

__device__ __forceinline__ float bf2f(unsigned short u) {
    unsigned v = ((unsigned)u) << 16;
    return __builtin_bit_cast(float, v);
}
__device__ __forceinline__ unsigned short f2bf(float f) {
    unsigned x = __builtin_bit_cast(unsigned, f);
    unsigned r = (x + 0x7fffu + ((x >> 16) & 1u)) >> 16;  // RTN-even
    return (unsigned short)r;
}

// ---------------- CSR build ----------------

__global__ void zero_int_kernel(int* __restrict__ p, int n) {
    int i = blockIdx.x * 256 + threadIdx.x;
    if (i < n) p[i] = 0;
}

__global__ void deg_kernel(const int* __restrict__ dst, int* __restrict__ deg) {
    int e = blockIdx.x * 256 + threadIdx.x;
    if (e < N_EDGES) atomicAdd(&deg[dst[e]], 1);
}

__global__ __launch_bounds__(1024) void scan_blk_kernel(const int* __restrict__ deg,
                                                        int* __restrict__ partial,
                                                        int* __restrict__ bsum) {
    __shared__ int tmp[1024];
    int tid = threadIdx.x;
    int i = blockIdx.x * 1024 + tid;
    int v = (i < N_NODES) ? deg[i] : 0;
    tmp[tid] = v;
    __syncthreads();
    for (int off = 1; off < 1024; off <<= 1) {
        int add = (tid >= off) ? tmp[tid - off] : 0;
        __syncthreads();
        tmp[tid] += add;
        __syncthreads();
    }
    if (i < N_NODES) partial[i] = tmp[tid] - v;
    if (tid == 1023) bsum[blockIdx.x] = tmp[tid];
}

__global__ void scan_top_kernel(const int* __restrict__ bsum, int* __restrict__ boff,
                                int* __restrict__ row_start, int nblk) {
    int l = threadIdx.x;
    int v = (l < nblk) ? bsum[l] : 0;
    int incl = v;
#pragma unroll
    for (int m = 1; m < 64; m <<= 1) {
        int t = __shfl_up(incl, m);
        if (l >= m) incl += t;
    }
    if (l < nblk) boff[l] = incl - v;
    if (l == 63) row_start[N_NODES] = incl;
}

__global__ void scan_fix_kernel(const int* __restrict__ partial, const int* __restrict__ boff,
                                const int* __restrict__ deg, int* __restrict__ row_start,
                                int* __restrict__ cursor, float* __restrict__ deg_inv) {
    int i = blockIdx.x * 256 + threadIdx.x;
    if (i >= N_NODES) return;
    int rs = partial[i] + boff[i >> 10];
    row_start[i] = rs;
    cursor[i] = rs;
    deg_inv[i] = 1.0f / fmaxf((float)deg[i], 1.0f);
}

__global__ void fill_kernel(const int* __restrict__ src, const int* __restrict__ dst,
                            int* __restrict__ cursor, int* __restrict__ csr_src) {
    int e = blockIdx.x * 256 + threadIdx.x;
    if (e < N_EDGES) {
        int slot = atomicAdd(&cursor[dst[e]], 1);
        csr_src[slot] = src[e];
    }
}

// ---------------- weight pack: fragment-major bf16 [conv][kt][ct][lane][8] ----------------

__global__ void pack_w_kernel(const float* __restrict__ Wl1, const float* __restrict__ Wr1,
                              const float* __restrict__ Wl2, const float* __restrict__ Wr2,
                              unsigned short* __restrict__ Wp) {
    int tid = blockIdx.x * 256 + threadIdx.x;  // < 65536
    int conv = tid >> 15;
    int e = tid & 32767;
    int j = e & 7, lane = (e >> 3) & 63, ct = (e >> 9) & 3, kt = e >> 11;
    int k = kt * 16 + (lane >> 5) * 8 + j;
    int col = ct * 32 + (lane & 31);
    const float* Wl = conv ? Wl2 : Wl1;
    const float* Wr = conv ? Wr2 : Wr1;
    float v = (k < 128) ? Wl[k * 128 + col] : Wr[(k - 128) * 128 + col];
    Wp[tid] = f2bf(v);
}

// ---------------- pre layer: h0 = relu(x @ W_pre + b_pre) -> bf16 (vectorized) ----------------

__global__ void pre_kernel(const float* __restrict__ x, const float* __restrict__ Wp,
                           const float* __restrict__ bp, unsigned short* __restrict__ h0) {
    int idx = blockIdx.x * 256 + threadIdx.x;  // node*32 + slot
    if (idx >= N_NODES * 32) return;
    int node = idx >> 5, j4 = (idx & 31) * 4;
    const float* xr = x + node * 5;
    float4 acc = *(const float4*)&bp[j4];
#pragma unroll
    for (int k = 0; k < 5; ++k) {
        float xv = xr[k];
        float4 w = *(const float4*)&Wp[k * D + j4];
        acc.x += xv * w.x; acc.y += xv * w.y; acc.z += xv * w.z; acc.w += xv * w.w;
    }
    ushort4 o;
    o.x = f2bf(fmaxf(acc.x, 0.f));
    o.y = f2bf(fmaxf(acc.y, 0.f));
    o.z = f2bf(fmaxf(acc.z, 0.f));
    o.w = f2bf(fmaxf(acc.w, 0.f));
    *(ushort4*)&h0[(size_t)node * D + j4] = o;
}

// ---------------- mean aggregate: 4 edge-chains/wave, 16B loads, 2x unroll ----------------

__global__ __launch_bounds__(256) void agg_kernel(const unsigned short* __restrict__ h,
                                                  const int* __restrict__ row_start,
                                                  const int* __restrict__ csr_src,
                                                  const float* __restrict__ deg_inv,
                                                  unsigned short* __restrict__ aggb) {
    int node = blockIdx.x * 4 + (threadIdx.x >> 6);
    int lane = threadIdx.x & 63;
    if (node >= N_NODES) return;
    int grp = lane >> 4;   // 0..3: which edge-chain
    int fl = lane & 15;    // feature slot: features fl*8 .. fl*8+7
    int s = row_start[node], e = row_start[node + 1];
    float a[8] = {0.f, 0.f, 0.f, 0.f, 0.f, 0.f, 0.f, 0.f};
    int i = s + grp;
    for (; i + 4 < e; i += 8) {
        int c0 = csr_src[i];
        int c1 = csr_src[i + 4];
        bf16x8 v0 = *(const bf16x8*)(h + (size_t)c0 * D + fl * 8);
        bf16x8 v1 = *(const bf16x8*)(h + (size_t)c1 * D + fl * 8);
#pragma unroll
        for (int j = 0; j < 8; ++j) a[j] += (float)v0[j] + (float)v1[j];
    }
    if (i < e) {
        int c0 = csr_src[i];
        bf16x8 v0 = *(const bf16x8*)(h + (size_t)c0 * D + fl * 8);
#pragma unroll
        for (int j = 0; j < 8; ++j) a[j] += (float)v0[j];
    }
#pragma unroll
    for (int j = 0; j < 8; ++j) {
        a[j] += __shfl_xor(a[j], 16);
        a[j] += __shfl_xor(a[j], 32);
    }
    if (grp == 0) {
        float di = deg_inv[node];
        u16x8 o;
#pragma unroll
        for (int j = 0; j < 8; ++j) o[j] = f2bf(a[j] * di);
        *(u16x8*)(aggb + (size_t)node * D + fl * 8) = o;
    }
}

// ---------------- fused SAGE linear via MFMA (no LDS, no barriers) ----------------

__global__ __launch_bounds__(256) void lin_mfma_kernel(const unsigned short* __restrict__ hin,
                                                       const unsigned short* __restrict__ aggb,
                                                       const unsigned short* __restrict__ Wp,
                                                       const float* __restrict__ b,
                                                       unsigned short* __restrict__ hout) {
    int wg = blockIdx.x * 4 + (threadIdx.x >> 6);
    if (wg >= NTILES) return;
    int lane = threadIdx.x & 63;
    int l31 = lane & 31, hi = lane >> 5;
    int row0 = wg * 32;
    int rowg = row0 + l31;
    if (rowg > N_NODES - 1) rowg = N_NODES - 1;

    const unsigned short* arow = aggb + (size_t)rowg * D + hi * 8;
    const unsigned short* hrow = hin + (size_t)rowg * D + hi * 8;
    const unsigned short* wbase = Wp + lane * 8;

    f32x16 acc[4];
#pragma unroll
    for (int ct = 0; ct < 4; ++ct) acc[ct] = (f32x16)(0.0f);

#pragma unroll
    for (int kt = 0; kt < 16; ++kt) {
        const unsigned short* asrc = (kt < 8) ? (arow + kt * 16) : (hrow + (kt - 8) * 16);
        bf16x8 af = *(const bf16x8*)asrc;
#pragma unroll
        for (int ct = 0; ct < 4; ++ct) {
            bf16x8 bfrag = *(const bf16x8*)(wbase + (kt * 4 + ct) * 512);
            acc[ct] = __builtin_amdgcn_mfma_f32_32x32x16_bf16(af, bfrag, acc[ct], 0, 0, 0);
        }
    }

    float bb[4];
#pragma unroll
    for (int ct = 0; ct < 4; ++ct) bb[ct] = b[ct * 32 + l31];

#pragma unroll
    for (int r = 0; r < 16; ++r) {
        float v0 = acc[0][r] + bb[0];
        float v1 = acc[1][r] + bb[1];
        float v2 = acc[2][r] + bb[2];
        float v3 = acc[3][r] + bb[3];
        float ss = v0 * v0 + v1 * v1 + v2 * v2 + v3 * v3;
        ss += __shfl_xor(ss, 1);
        ss += __shfl_xor(ss, 2);
        ss += __shfl_xor(ss, 4);
        ss += __shfl_xor(ss, 8);
        ss += __shfl_xor(ss, 16);
        float sc = 1.0f / fmaxf(sqrtf(ss), 1e-12f);
        int row = row0 + (r & 3) + 8 * (r >> 2) + 4 * hi;
        if (row < N_NODES) {
            size_t o = (size_t)row * D + l31;
            hout[o] = f2bf(fmaxf(v0 * sc, 0.f));
            hout[o + 32] = f2bf(fmaxf(v1 * sc, 0.f));
            hout[o + 64] = f2bf(fmaxf(v2 * sc, 0.f));
            hout[o + 96] = f2bf(fmaxf(v3 * sc, 0.f));
        }
    }
}

// ---------------- global mean pool: chunk-parallel run-length atomics ----------------

__global__ __launch_bounds__(128) void pool_sum_kernel(const unsigned short* __restrict__ h,
                                                       const int* __restrict__ batch,
                                                       float* __restrict__ gsum) {
    int j = threadIdx.x;
    int i0 = blockIdx.x * 128;
    int i1 = i0 + 128;
    if (i1 > N_NODES) i1 = N_NODES;
    __shared__ int bids[128];
    if (i0 + j < N_NODES) bids[j] = batch[i0 + j];
    __syncthreads();
    float acc = 0.f;
    int cur = bids[0];
    for (int i = i0; i < i1; ++i) {
        int bid = bids[i - i0];
        if (bid != cur) {
            atomicAdd(&gsum[cur * D + j], acc);
            acc = 0.f;
            cur = bid;
        }
        acc += bf2f(h[(size_t)i * D + j]);
    }
    atomicAdd(&gsum[cur * D + j], acc);
}

// ---------------- head MLP (f32), fused mean-divide via binary search ----------------

__global__ __launch_bounds__(128) void mlp_kernel(const float* __restrict__ gsum,
                                                  const int* __restrict__ batch,
                                                  const float* __restrict__ Wp1,
                                                  const float* __restrict__ bp1,
                                                  const float* __restrict__ Wp2,
                                                  const float* __restrict__ bp2,
                                                  const float* __restrict__ Wout,
                                                  const float* __restrict__ bout,
                                                  float* __restrict__ out) {
    __shared__ float gin[128], y1[128], y2[64];
    __shared__ float cnt_s;
    int gid = blockIdx.x, j = threadIdx.x;
    if (j == 0) {
        int lo = 0, hi = N_NODES;
        while (lo < hi) { int m = (lo + hi) >> 1; if (batch[m] < gid) lo = m + 1; else hi = m; }
        int start = lo;
        lo = start; hi = N_NODES;
        while (lo < hi) { int m = (lo + hi) >> 1; if (batch[m] < gid + 1) lo = m + 1; else hi = m; }
        cnt_s = fmaxf((float)(lo - start), 1.0f);
    }
    __syncthreads();
    gin[j] = gsum[gid * 128 + j] / cnt_s;
    __syncthreads();
    float a = bp1[j];
    for (int k = 0; k < 128; ++k) a += gin[k] * Wp1[k * 128 + j];
    y1[j] = fmaxf(a, 0.f);
    __syncthreads();
    if (j < 64) {
        float a2 = bp2[j];
        for (int k = 0; k < 128; ++k) a2 += y1[k] * Wp2[k * 64 + j];
        y2[j] = fmaxf(a2, 0.f);
    }
    __syncthreads();
    if (j < 64) {
        float v = y2[j] * Wout[j];
#pragma unroll
        for (int m = 32; m >= 1; m >>= 1) v += __shfl_xor(v, m);
        if (j == 0) out[gid] = v + bout[0];
    }
}

// ---------------- launch ----------------

extern "C" void kernel_launch(void* const* d_in, const int* in_sizes, int n_in,
                              void* d_out, int out_size, void* d_ws, size_t ws_size,
                              hipStream_t stream) {
    const float* x     = (const float*)d_in[0];
    const int*   ei    = (const int*)d_in[1];
    const int*   batch = (const int*)d_in[2];
    const float* W_pre = (const float*)d_in[3];
    const float* b_pre = (const float*)d_in[4];
    const float* W1_l  = (const float*)d_in[5];
    const float* b1    = (const float*)d_in[6];
    const float* W1_r  = (const float*)d_in[7];
    const float* W2_l  = (const float*)d_in[8];
    const float* b2    = (const float*)d_in[9];
    const float* W2_r  = (const float*)d_in[10];
    const float* W_p1  = (const float*)d_in[11];
    const float* b_p1  = (const float*)d_in[12];
    const float* W_p2  = (const float*)d_in[13];
    const float* b_p2  = (const float*)d_in[14];
    const float* W_out = (const float*)d_in[15];
    const float* b_out = (const float*)d_in[16];

    const int* src = ei;
    const int* dst = ei + N_EDGES;

    size_t off = 0;
    auto carve = [&](size_t bytes) {
        void* p = (char*)d_ws + off;
        off += (bytes + 255) & ~(size_t)255;
        return p;
    };
    // deg (50048 ints, padded) immediately followed by gsum (32768 f32) so one
    // zero_int launch clears both.
    int* deg       = (int*)carve(50048 * 4 + 32768 * 4);
    float* gsum    = (float*)(deg + 50048);
    int* row_start = (int*)carve((N_NODES + 1) * 4);
    int* cursor    = (int*)carve(N_NODES * 4);
    int* csr_src   = (int*)carve(N_EDGES * 4);
    float* deg_inv = (float*)carve(N_NODES * 4);
    int* partial   = (int*)carve(N_NODES * 4);
    int* bsum      = (int*)carve(64 * 4);
    int* boff      = (int*)carve(64 * 4);
    unsigned short* h0   = (unsigned short*)carve((size_t)N_NODES * D * 2);
    unsigned short* h1   = (unsigned short*)carve((size_t)N_NODES * D * 2);
    unsigned short* aggb = (unsigned short*)carve((size_t)N_NODES * D * 2);
    unsigned short* Wp   = (unsigned short*)carve(65536 * 2);
    unsigned short* h2 = h0;  // reuse
    float* out = (float*)d_out;

    const int nblk_scan = (N_NODES + 1023) / 1024;  // 49

    pack_w_kernel<<<256, 256, 0, stream>>>(W1_l, W1_r, W2_l, W2_r, Wp);

    zero_int_kernel<<<(50048 + 32768 + 255) / 256, 256, 0, stream>>>(deg, 50048 + 32768);
    deg_kernel<<<(N_EDGES + 255) / 256, 256, 0, stream>>>(dst, deg);
    scan_blk_kernel<<<nblk_scan, 1024, 0, stream>>>(deg, partial, bsum);
    scan_top_kernel<<<1, 64, 0, stream>>>(bsum, boff, row_start, nblk_scan);
    scan_fix_kernel<<<(N_NODES + 255) / 256, 256, 0, stream>>>(partial, boff, deg,
                                                               row_start, cursor, deg_inv);
    fill_kernel<<<(N_EDGES + 255) / 256, 256, 0, stream>>>(src, dst, cursor, csr_src);

    pre_kernel<<<(N_NODES * 32 + 255) / 256, 256, 0, stream>>>(x, W_pre, b_pre, h0);

    // conv1
    agg_kernel<<<(N_NODES + 3) / 4, 256, 0, stream>>>(h0, row_start, csr_src, deg_inv, aggb);
    lin_mfma_kernel<<<(NTILES + 3) / 4, 256, 0, stream>>>(h0, aggb, Wp, b1, h1);

    // conv2
    agg_kernel<<<(N_NODES + 3) / 4, 256, 0, stream>>>(h1, row_start, csr_src, deg_inv, aggb);
    lin_mfma_kernel<<<(NTILES + 3) / 4, 256, 0, stream>>>(h1, aggb, Wp + 32768, b2, h2);

    // pool + head
    pool_sum_kernel<<<(N_NODES + 127) / 128, 128, 0, stream>>>(h2, batch, gsum);
    mlp_kernel<<<N_GRAPHS, 128, 0, stream>>>(gsum, batch, W_p1, b_p1, W_p2, b_p2,
                                             W_out, b_out, out);
}

// Round 4
// 215.305 us; speedup vs baseline: 2.6176x; 1.0473x over previous
//
#include <hip/hip_runtime.h>
#include <hip/hip_bf16.h>

#define N_NODES 50000
#define N_EDGES 600000
#define N_GRAPHS 256
#define D 128
#define NTILES 1563  // ceil(50000/32)

typedef __bf16 bf16x8 __attribute__((ext_vector_type(8)));
typedef float f32x16 __attribute__((ext_vector_type(16)));
typedef unsigned short u16x8 __attribute__((ext_vector_type(8)));
typedef unsigned short u16x4 __attribute__((ext_vector_type(4)));

__device__ __forceinline__ float bf2f(unsigned short u) {
    unsigned v = ((unsigned)u) << 16;
    return __builtin_bit_cast(float, v);
}
__device__ __forceinline__ unsigned short f2bf(float f) {
    unsigned x = __builtin_bit_cast(unsigned, f);
    unsigned r = (x + 0x7fffu + ((x >> 16) & 1u)) >> 16;  // RTN-even
    return (unsigned short)r;
}

// ---------------- CSR build ----------------

__global__ void zero_int_kernel(int* __restrict__ p, int n) {
    int i = blockIdx.x * 256 + threadIdx.x;
    if (i < n) p[i] = 0;
}

__global__ void deg_kernel(const int* __restrict__ dst, int* __restrict__ deg) {
    int e = blockIdx.x * 256 + threadIdx.x;
    if (e < N_EDGES) atomicAdd(&deg[dst[e]], 1);
}

__global__ __launch_bounds__(1024) void scan_blk_kernel(const int* __restrict__ deg,
                                                        int* __restrict__ partial,
                                                        int* __restrict__ bsum) {
    __shared__ int tmp[1024];
    int tid = threadIdx.x;
    int i = blockIdx.x * 1024 + tid;
    int v = (i < N_NODES) ? deg[i] : 0;
    tmp[tid] = v;
    __syncthreads();
    for (int off = 1; off < 1024; off <<= 1) {
        int add = (tid >= off) ? tmp[tid - off] : 0;
        __syncthreads();
        tmp[tid] += add;
        __syncthreads();
    }
    if (i < N_NODES) partial[i] = tmp[tid] - v;
    if (tid == 1023) bsum[blockIdx.x] = tmp[tid];
}

__global__ void scan_top_kernel(const int* __restrict__ bsum, int* __restrict__ boff,
                                int* __restrict__ row_start, int nblk) {
    int l = threadIdx.x;
    int v = (l < nblk) ? bsum[l] : 0;
    int incl = v;
#pragma unroll
    for (int m = 1; m < 64; m <<= 1) {
        int t = __shfl_up(incl, m);
        if (l >= m) incl += t;
    }
    if (l < nblk) boff[l] = incl - v;
    if (l == 63) row_start[N_NODES] = incl;
}

__global__ void scan_fix_kernel(const int* __restrict__ partial, const int* __restrict__ boff,
                                const int* __restrict__ deg, int* __restrict__ row_start,
                                int* __restrict__ cursor, float* __restrict__ deg_inv) {
    int i = blockIdx.x * 256 + threadIdx.x;
    if (i >= N_NODES) return;
    int rs = partial[i] + boff[i >> 10];
    row_start[i] = rs;
    cursor[i] = rs;
    deg_inv[i] = 1.0f / fmaxf((float)deg[i], 1.0f);
}

__global__ void fill_kernel(const int* __restrict__ src, const int* __restrict__ dst,
                            int* __restrict__ cursor, int* __restrict__ csr_src) {
    int e = blockIdx.x * 256 + threadIdx.x;
    if (e < N_EDGES) {
        int slot = atomicAdd(&cursor[dst[e]], 1);
        csr_src[slot] = src[e];
    }
}

// ---------------- weight pack: fragment-major bf16 [conv][kt][ct][lane][8] ----------------
// B-frag for mfma_f32_32x32x16_bf16 at (kt,ct): lane l, elem j holds
//   W[kt*16 + (l>>5)*8 + j][ logical col = (l&31)*4 + ct ]
// (so each output lane owns 4 consecutive columns across its 4 ct-fragments)

__global__ void pack_w_kernel(const float* __restrict__ Wl1, const float* __restrict__ Wr1,
                              const float* __restrict__ Wl2, const float* __restrict__ Wr2,
                              unsigned short* __restrict__ Wp) {
    int tid = blockIdx.x * 256 + threadIdx.x;  // < 65536
    int conv = tid >> 15;
    int e = tid & 32767;
    int j = e & 7, lane = (e >> 3) & 63, ct = (e >> 9) & 3, kt = e >> 11;
    int k = kt * 16 + (lane >> 5) * 8 + j;
    int col = (lane & 31) * 4 + ct;
    const float* Wl = conv ? Wl2 : Wl1;
    const float* Wr = conv ? Wr2 : Wr1;
    float v = (k < 128) ? Wl[k * 128 + col] : Wr[(k - 128) * 128 + col];
    Wp[tid] = f2bf(v);
}

// ---------------- pre layer: h0 = relu(x @ W_pre + b_pre) -> bf16 (8-wide) ----------------

__global__ void pre_kernel(const float* __restrict__ x, const float* __restrict__ Wp,
                           const float* __restrict__ bp, unsigned short* __restrict__ h0) {
    int idx = blockIdx.x * 256 + threadIdx.x;  // node*16 + slot
    if (idx >= N_NODES * 16) return;
    int node = idx >> 4, j8 = (idx & 15) * 8;
    const float* xr = x + node * 5;
    float acc[8];
#pragma unroll
    for (int c = 0; c < 8; ++c) acc[c] = bp[j8 + c];
#pragma unroll
    for (int k = 0; k < 5; ++k) {
        float xv = xr[k];
#pragma unroll
        for (int c = 0; c < 8; ++c) acc[c] += xv * Wp[k * D + j8 + c];
    }
    u16x8 o;
#pragma unroll
    for (int c = 0; c < 8; ++c) o[c] = f2bf(fmaxf(acc[c], 0.f));
    *(u16x8*)&h0[(size_t)node * D + j8] = o;
}

// ---------------- mean aggregate: one node per 16-lane group, 4-wide unroll ----------------

__global__ __launch_bounds__(256) void agg_kernel(const unsigned short* __restrict__ h,
                                                  const int* __restrict__ row_start,
                                                  const int* __restrict__ csr_src,
                                                  const float* __restrict__ deg_inv,
                                                  unsigned short* __restrict__ aggb) {
    int node = blockIdx.x * 16 + (threadIdx.x >> 4);
    int fl = threadIdx.x & 15;  // feature slot: features fl*8 .. fl*8+7
    if (node >= N_NODES) return;
    int s = row_start[node], e = row_start[node + 1];
    float a[8] = {0.f, 0.f, 0.f, 0.f, 0.f, 0.f, 0.f, 0.f};
    int i = s;
    for (; i + 3 < e; i += 4) {
        int c0 = csr_src[i];
        int c1 = csr_src[i + 1];
        int c2 = csr_src[i + 2];
        int c3 = csr_src[i + 3];
        bf16x8 v0 = *(const bf16x8*)(h + (size_t)c0 * D + fl * 8);
        bf16x8 v1 = *(const bf16x8*)(h + (size_t)c1 * D + fl * 8);
        bf16x8 v2 = *(const bf16x8*)(h + (size_t)c2 * D + fl * 8);
        bf16x8 v3 = *(const bf16x8*)(h + (size_t)c3 * D + fl * 8);
#pragma unroll
        for (int j = 0; j < 8; ++j)
            a[j] += ((float)v0[j] + (float)v1[j]) + ((float)v2[j] + (float)v3[j]);
    }
    for (; i < e; ++i) {
        int c0 = csr_src[i];
        bf16x8 v0 = *(const bf16x8*)(h + (size_t)c0 * D + fl * 8);
#pragma unroll
        for (int j = 0; j < 8; ++j) a[j] += (float)v0[j];
    }
    float di = deg_inv[node];
    u16x8 o;
#pragma unroll
    for (int j = 0; j < 8; ++j) o[j] = f2bf(a[j] * di);
    *(u16x8*)(aggb + (size_t)node * D + fl * 8) = o;
}

// ---------------- fused SAGE linear via MFMA (no LDS, no barriers) ----------------

__global__ __launch_bounds__(256) void lin_mfma_kernel(const unsigned short* __restrict__ hin,
                                                       const unsigned short* __restrict__ aggb,
                                                       const unsigned short* __restrict__ Wp,
                                                       const float* __restrict__ b,
                                                       unsigned short* __restrict__ hout) {
    int wg = blockIdx.x * 4 + (threadIdx.x >> 6);
    if (wg >= NTILES) return;
    int lane = threadIdx.x & 63;
    int l31 = lane & 31, hi = lane >> 5;
    int row0 = wg * 32;
    int rowg = row0 + l31;
    if (rowg > N_NODES - 1) rowg = N_NODES - 1;

    const unsigned short* arow = aggb + (size_t)rowg * D + hi * 8;
    const unsigned short* hrow = hin + (size_t)rowg * D + hi * 8;
    const unsigned short* wbase = Wp + lane * 8;

    f32x16 acc[4];
#pragma unroll
    for (int ct = 0; ct < 4; ++ct) acc[ct] = (f32x16)(0.0f);

#pragma unroll
    for (int kt = 0; kt < 16; ++kt) {
        const unsigned short* asrc = (kt < 8) ? (arow + kt * 16) : (hrow + (kt - 8) * 16);
        bf16x8 af = *(const bf16x8*)asrc;
#pragma unroll
        for (int ct = 0; ct < 4; ++ct) {
            bf16x8 bfrag = *(const bf16x8*)(wbase + (kt * 4 + ct) * 512);
            acc[ct] = __builtin_amdgcn_mfma_f32_32x32x16_bf16(af, bfrag, acc[ct], 0, 0, 0);
        }
    }

    // epilogue: +bias, per-row L2 norm, relu, 8B vector store (4 consecutive cols/lane)
    float4 b4 = *(const float4*)&b[l31 * 4];
    float bb[4] = {b4.x, b4.y, b4.z, b4.w};

#pragma unroll
    for (int r = 0; r < 16; ++r) {
        float v[4];
        float ss = 0.f;
#pragma unroll
        for (int ct = 0; ct < 4; ++ct) {
            v[ct] = acc[ct][r] + bb[ct];
            ss += v[ct] * v[ct];
        }
        ss += __shfl_xor(ss, 1);
        ss += __shfl_xor(ss, 2);
        ss += __shfl_xor(ss, 4);
        ss += __shfl_xor(ss, 8);
        ss += __shfl_xor(ss, 16);
        float sc = 1.0f / fmaxf(sqrtf(ss), 1e-12f);
        int row = row0 + (r & 3) + 8 * (r >> 2) + 4 * hi;
        if (row < N_NODES) {
            u16x4 o;
#pragma unroll
            for (int ct = 0; ct < 4; ++ct) o[ct] = f2bf(fmaxf(v[ct] * sc, 0.f));
            *(u16x4*)(hout + (size_t)row * D + l31 * 4) = o;
        }
    }
}

// ---------------- global mean pool: chunk-parallel run-length atomics ----------------

__global__ __launch_bounds__(128) void pool_sum_kernel(const unsigned short* __restrict__ h,
                                                       const int* __restrict__ batch,
                                                       float* __restrict__ gsum) {
    int j = threadIdx.x;
    int i0 = blockIdx.x * 128;
    int i1 = i0 + 128;
    if (i1 > N_NODES) i1 = N_NODES;
    __shared__ int bids[128];
    if (i0 + j < N_NODES) bids[j] = batch[i0 + j];
    __syncthreads();
    float acc = 0.f;
    int cur = bids[0];
    for (int i = i0; i < i1; ++i) {
        int bid = bids[i - i0];
        if (bid != cur) {
            atomicAdd(&gsum[cur * D + j], acc);
            acc = 0.f;
            cur = bid;
        }
        acc += bf2f(h[(size_t)i * D + j]);
    }
    atomicAdd(&gsum[cur * D + j], acc);
}

// ---------------- head MLP (f32), fused mean-divide via binary search ----------------

__global__ __launch_bounds__(128) void mlp_kernel(const float* __restrict__ gsum,
                                                  const int* __restrict__ batch,
                                                  const float* __restrict__ Wp1,
                                                  const float* __restrict__ bp1,
                                                  const float* __restrict__ Wp2,
                                                  const float* __restrict__ bp2,
                                                  const float* __restrict__ Wout,
                                                  const float* __restrict__ bout,
                                                  float* __restrict__ out) {
    __shared__ float gin[128], y1[128], y2[64];
    __shared__ float cnt_s;
    int gid = blockIdx.x, j = threadIdx.x;
    if (j == 0) {
        int lo = 0, hi = N_NODES;
        while (lo < hi) { int m = (lo + hi) >> 1; if (batch[m] < gid) lo = m + 1; else hi = m; }
        int start = lo;
        lo = start; hi = N_NODES;
        while (lo < hi) { int m = (lo + hi) >> 1; if (batch[m] < gid + 1) lo = m + 1; else hi = m; }
        cnt_s = fmaxf((float)(lo - start), 1.0f);
    }
    __syncthreads();
    gin[j] = gsum[gid * 128 + j] / cnt_s;
    __syncthreads();
    float a = bp1[j];
    for (int k = 0; k < 128; ++k) a += gin[k] * Wp1[k * 128 + j];
    y1[j] = fmaxf(a, 0.f);
    __syncthreads();
    if (j < 64) {
        float a2 = bp2[j];
        for (int k = 0; k < 128; ++k) a2 += y1[k] * Wp2[k * 64 + j];
        y2[j] = fmaxf(a2, 0.f);
    }
    __syncthreads();
    if (j < 64) {
        float v = y2[j] * Wout[j];
#pragma unroll
        for (int m = 32; m >= 1; m >>= 1) v += __shfl_xor(v, m);
        if (j == 0) out[gid] = v + bout[0];
    }
}

// ---------------- launch ----------------

extern "C" void kernel_launch(void* const* d_in, const int* in_sizes, int n_in,
                              void* d_out, int out_size, void* d_ws, size_t ws_size,
                              hipStream_t stream) {
    const float* x     = (const float*)d_in[0];
    const int*   ei    = (const int*)d_in[1];
    const int*   batch = (const int*)d_in[2];
    const float* W_pre = (const float*)d_in[3];
    const float* b_pre = (const float*)d_in[4];
    const float* W1_l  = (const float*)d_in[5];
    const float* b1    = (const float*)d_in[6];
    const float* W1_r  = (const float*)d_in[7];
    const float* W2_l  = (const float*)d_in[8];
    const float* b2    = (const float*)d_in[9];
    const float* W2_r  = (const float*)d_in[10];
    const float* W_p1  = (const float*)d_in[11];
    const float* b_p1  = (const float*)d_in[12];
    const float* W_p2  = (const float*)d_in[13];
    const float* b_p2  = (const float*)d_in[14];
    const float* W_out = (const float*)d_in[15];
    const float* b_out = (const float*)d_in[16];

    const int* src = ei;
    const int* dst = ei + N_EDGES;

    size_t off = 0;
    auto carve = [&](size_t bytes) {
        void* p = (char*)d_ws + off;
        off += (bytes + 255) & ~(size_t)255;
        return p;
    };
    // deg (50048 ints) + gsum (32768 f32) cleared by one zero_int launch
    int* deg       = (int*)carve(50048 * 4 + 32768 * 4);
    float* gsum    = (float*)(deg + 50048);
    int* row_start = (int*)carve((N_NODES + 1) * 4);
    int* cursor    = (int*)carve(N_NODES * 4);
    int* csr_src   = (int*)carve(N_EDGES * 4);
    float* deg_inv = (float*)carve(N_NODES * 4);
    int* partial   = (int*)carve(N_NODES * 4);
    int* bsum      = (int*)carve(64 * 4);
    int* boff      = (int*)carve(64 * 4);
    unsigned short* h0   = (unsigned short*)carve((size_t)N_NODES * D * 2);
    unsigned short* h1   = (unsigned short*)carve((size_t)N_NODES * D * 2);
    unsigned short* aggb = (unsigned short*)carve((size_t)N_NODES * D * 2);
    unsigned short* Wp   = (unsigned short*)carve(65536 * 2);
    unsigned short* h2 = h0;  // reuse
    float* out = (float*)d_out;

    const int nblk_scan = (N_NODES + 1023) / 1024;  // 49

    pack_w_kernel<<<256, 256, 0, stream>>>(W1_l, W1_r, W2_l, W2_r, Wp);

    zero_int_kernel<<<(50048 + 32768 + 255) / 256, 256, 0, stream>>>(deg, 50048 + 32768);
    deg_kernel<<<(N_EDGES + 255) / 256, 256, 0, stream>>>(dst, deg);
    scan_blk_kernel<<<nblk_scan, 1024, 0, stream>>>(deg, partial, bsum);
    scan_top_kernel<<<1, 64, 0, stream>>>(bsum, boff, row_start, nblk_scan);
    scan_fix_kernel<<<(N_NODES + 255) / 256, 256, 0, stream>>>(partial, boff, deg,
                                                               row_start, cursor, deg_inv);
    fill_kernel<<<(N_EDGES + 255) / 256, 256, 0, stream>>>(src, dst, cursor, csr_src);

    pre_kernel<<<(N_NODES * 16 + 255) / 256, 256, 0, stream>>>(x, W_pre, b_pre, h0);

    // conv1
    agg_kernel<<<(N_NODES + 15) / 16, 256, 0, stream>>>(h0, row_start, csr_src, deg_inv, aggb);
    lin_mfma_kernel<<<(NTILES + 3) / 4, 256, 0, stream>>>(h0, aggb, Wp, b1, h1);

    // conv2
    agg_kernel<<<(N_NODES + 15) / 16, 256, 0, stream>>>(h1, row_start, csr_src, deg_inv, aggb);
    lin_mfma_kernel<<<(NTILES + 3) / 4, 256, 0, stream>>>(h1, aggb, Wp + 32768, b2, h2);

    // pool + head
    pool_sum_kernel<<<(N_NODES + 127) / 128, 128, 0, stream>>>(h2, batch, gsum);
    mlp_kernel<<<N_GRAPHS, 128, 0, stream>>>(gsum, batch, W_p1, b_p1, W_p2, b_p2,
                                             W_out, b_out, out);
}